// Round 1
// baseline (124.826 us; speedup 1.0000x reference)
//
#include <hip/hip_runtime.h>

// MeanAggregator: out[b,:] = mean over UNIQUE cols c in row-segment b of embed[c,:]
// row_idx sorted ascending; duplicates of (row,col) count once (.set semantics).
//
// B = 4096 rows (blocks), U = 50000, D = 300, E = 131072 (avg deg 32).
// One wave (64 threads) per row:
//   - binary search segment [start,end) in sorted row_idx
//   - stage segment cols in LDS (cap 1024 >> max realistic deg ~70; global fallback)
//   - per edge: wave-parallel dup check vs earlier cols, then float4 gather-accum
//     of embed row (75 float4 chunks; lane t -> chunk t, lanes 0..10 -> chunk 64+t)

#define DFEAT 300
#define NCHUNK 75        // DFEAT / 4
#define COLS_CAP 1024    // LDS staging capacity for a row's cols

__global__ __launch_bounds__(64) void mean_agg_kernel(
    const int* __restrict__ row_idx,
    const int* __restrict__ col_idx,
    const float* __restrict__ embed,
    float* __restrict__ out,
    int E)
{
    const int b = blockIdx.x;
    const int t = threadIdx.x;   // 0..63

    // lower_bound(row_idx, b) and lower_bound(row_idx, b+1); wave-uniform.
    int lo = 0, hi = E;
    while (lo < hi) { int m = (lo + hi) >> 1; if (row_idx[m] < b)     lo = m + 1; else hi = m; }
    const int start = lo;
    hi = E;
    while (lo < hi) { int m = (lo + hi) >> 1; if (row_idx[m] < b + 1) lo = m + 1; else hi = m; }
    const int end = lo;
    const int deg = end - start;

    __shared__ int s_cols[COLS_CAP];
    for (int k = t; k < deg && k < COLS_CAP; k += 64) s_cols[k] = col_idx[start + k];
    __syncthreads();

    float4 acc0 = {0.f, 0.f, 0.f, 0.f};
    float4 acc1 = {0.f, 0.f, 0.f, 0.f};
    int count = 0;   // wave-uniform unique-neighbor count

    for (int e = 0; e < deg; ++e) {
        const int c = (e < COLS_CAP) ? s_cols[e] : col_idx[start + e];  // broadcast
        // wave-parallel duplicate check against earlier cols in this segment
        int dup = 0;
        for (int i = t; i < e; i += 64) {
            const int ci = (i < COLS_CAP) ? s_cols[i] : col_idx[start + i];
            dup |= (ci == c);
        }
        if (!__any(dup)) {
            const float4* __restrict__ rowp =
                (const float4*)(embed + (long long)c * DFEAT);  // 1200B rows: 16B-aligned
            const float4 v0 = rowp[t];
            acc0.x += v0.x; acc0.y += v0.y; acc0.z += v0.z; acc0.w += v0.w;
            if (t < NCHUNK - 64) {                 // lanes 0..10 cover chunks 64..74
                const float4 v1 = rowp[t + 64];
                acc1.x += v1.x; acc1.y += v1.y; acc1.z += v1.z; acc1.w += v1.w;
            }
            ++count;
        }
    }

    const float scale = (count > 0) ? (1.0f / (float)count) : 0.0f;
    float4* __restrict__ orow = (float4*)(out + (long long)b * DFEAT);
    float4 r0; r0.x = acc0.x * scale; r0.y = acc0.y * scale;
               r0.z = acc0.z * scale; r0.w = acc0.w * scale;
    orow[t] = r0;
    if (t < NCHUNK - 64) {
        float4 r1; r1.x = acc1.x * scale; r1.y = acc1.y * scale;
                   r1.z = acc1.z * scale; r1.w = acc1.w * scale;
        orow[t + 64] = r1;
    }
}

extern "C" void kernel_launch(void* const* d_in, const int* in_sizes, int n_in,
                              void* d_out, int out_size, void* d_ws, size_t ws_size,
                              hipStream_t stream) {
    const int*   row_idx = (const int*)  d_in[0];
    const int*   col_idx = (const int*)  d_in[1];
    const float* embed   = (const float*)d_in[2];
    float*       out     = (float*)      d_out;

    const int E = in_sizes[0];            // 131072
    const int B = out_size / DFEAT;       // 4096

    mean_agg_kernel<<<B, 64, 0, stream>>>(row_idx, col_idx, embed, out, E);
}

// Round 2
// 121.671 us; speedup vs baseline: 1.0259x; 1.0259x over previous
//
#include <hip/hip_runtime.h>

// MeanAggregator: out[b,:] = mean over UNIQUE cols c in row-segment b of embed[c,:]
// row_idx sorted ascending; duplicate (row,col) pairs count once (.set semantics).
//
// B = 4096 rows, U = 50000, D = 300, E = 131072 (avg deg 32, max ~60).
// One 256-thread block (4 waves) per row:
//   Phase 1: stage cols in LDS, dedup (back-check), compact unique list via LDS atomic
//   Phase 2: waves split unique cols, branch-free float4 gathers, 2-deep unrolled
//   Phase 3: LDS reduction of the 4 wave-partials, scale by 1/count, store

#define DFEAT  300
#define NCHUNK 75        // DFEAT / 4
#define COLS_CAP 512     // LDS staging capacity (max realistic deg ~60)
#define NWAVE  4

__global__ __launch_bounds__(256) void mean_agg_kernel(
    const int* __restrict__ row_idx,
    const int* __restrict__ col_idx,
    const float* __restrict__ embed,
    float* __restrict__ out,
    int E)
{
    const int b    = blockIdx.x;
    const int tid  = threadIdx.x;        // 0..255
    const int t    = tid & 63;           // lane
    const int wave = tid >> 6;           // 0..3

    // ---- segment bounds: lower_bound(b), lower_bound(b+1) (uniform) ----
    int lo = 0, hi = E;
    while (lo < hi) { int m = (lo + hi) >> 1; if (row_idx[m] < b)     lo = m + 1; else hi = m; }
    const int start = lo;
    hi = E;
    while (lo < hi) { int m = (lo + hi) >> 1; if (row_idx[m] < b + 1) lo = m + 1; else hi = m; }
    const int deg = lo - start;

    __shared__ int   s_cols[COLS_CAP];
    __shared__ int   s_uniq[COLS_CAP];
    __shared__ int   s_cnt;
    __shared__ float s_part[NWAVE][DFEAT];

    if (tid == 0) s_cnt = 0;
    for (int k = tid; k < deg && k < COLS_CAP; k += 256) s_cols[k] = col_idx[start + k];
    __syncthreads();

    // ---- Phase 1: dedup + compact (order in s_uniq doesn't matter) ----
    for (int k = tid; k < deg; k += 256) {
        const int c = (k < COLS_CAP) ? s_cols[k] : col_idx[start + k];
        bool dup = false;
        for (int i = 0; i < k; ++i) {
            const int ci = (i < COLS_CAP) ? s_cols[i] : col_idx[start + i];
            dup |= (ci == c);
        }
        if (!dup) {
            const int p = atomicAdd(&s_cnt, 1);
            if (p < COLS_CAP) s_uniq[p] = c;
        }
    }
    __syncthreads();
    const int cnt = s_cnt;

    // ---- Phase 2: branch-free gather, waves split unique cols ----
    float4 acc0 = {0.f, 0.f, 0.f, 0.f};
    float4 acc1 = {0.f, 0.f, 0.f, 0.f};
    const bool hi_lane = (t < NCHUNK - 64);   // lanes 0..10 cover chunks 64..74

    int u = wave;
    for (; u + NWAVE < cnt; u += 2 * NWAVE) {
        const float4* __restrict__ p0 = (const float4*)(embed + (long long)s_uniq[u] * DFEAT);
        const float4* __restrict__ p1 = (const float4*)(embed + (long long)s_uniq[u + NWAVE] * DFEAT);
        const float4 x0 = p0[t];
        const float4 y0 = p1[t];
        acc0.x += x0.x; acc0.y += x0.y; acc0.z += x0.z; acc0.w += x0.w;
        acc0.x += y0.x; acc0.y += y0.y; acc0.z += y0.z; acc0.w += y0.w;
        if (hi_lane) {
            const float4 x1 = p0[t + 64];
            const float4 y1 = p1[t + 64];
            acc1.x += x1.x; acc1.y += x1.y; acc1.z += x1.z; acc1.w += x1.w;
            acc1.x += y1.x; acc1.y += y1.y; acc1.z += y1.z; acc1.w += y1.w;
        }
    }
    if (u < cnt) {
        const float4* __restrict__ p0 = (const float4*)(embed + (long long)s_uniq[u] * DFEAT);
        const float4 x0 = p0[t];
        acc0.x += x0.x; acc0.y += x0.y; acc0.z += x0.z; acc0.w += x0.w;
        if (hi_lane) {
            const float4 x1 = p0[t + 64];
            acc1.x += x1.x; acc1.y += x1.y; acc1.z += x1.z; acc1.w += x1.w;
        }
    }

    // ---- Phase 3: cross-wave reduction in LDS ----
    *(float4*)&s_part[wave][4 * t] = acc0;
    if (hi_lane) *(float4*)&s_part[wave][256 + 4 * t] = acc1;
    __syncthreads();

    if (tid < NCHUNK) {
        const float scale = (cnt > 0) ? (1.0f / (float)cnt) : 0.0f;
        const int o = 4 * tid;
        float4 r = {0.f, 0.f, 0.f, 0.f};
        #pragma unroll
        for (int w = 0; w < NWAVE; ++w) {
            const float4 p = *(const float4*)&s_part[w][o];
            r.x += p.x; r.y += p.y; r.z += p.z; r.w += p.w;
        }
        r.x *= scale; r.y *= scale; r.z *= scale; r.w *= scale;
        *(float4*)(out + (long long)b * DFEAT + o) = r;
    }
}

extern "C" void kernel_launch(void* const* d_in, const int* in_sizes, int n_in,
                              void* d_out, int out_size, void* d_ws, size_t ws_size,
                              hipStream_t stream) {
    const int*   row_idx = (const int*)  d_in[0];
    const int*   col_idx = (const int*)  d_in[1];
    const float* embed   = (const float*)d_in[2];
    float*       out     = (float*)      d_out;

    const int E = in_sizes[0];            // 131072
    const int B = out_size / DFEAT;       // 4096

    mean_agg_kernel<<<B, 256, 0, stream>>>(row_idx, col_idx, embed, out, E);
}

// Round 3
// 112.238 us; speedup vs baseline: 1.1122x; 1.0840x over previous
//
#include <hip/hip_runtime.h>

// MeanAggregator: out[b,:] = mean over UNIQUE cols c in row-segment b of embed[c,:]
// row_idx sorted ascending; duplicate (row,col) pairs count once (.set semantics).
//
// B = 4096 rows, U = 50000, D = 300, E = 131072 (avg deg 32, max ~60).
//
// Kernel 1 (build_rowptr): CSR row pointers from sorted row_idx into d_ws.
//   Replaces the per-block binary search (34 DEPENDENT global loads ≈ 7-15k cyc
//   serial chain per block — the round-2 bottleneck) with 2 loads.
// Kernel 2 (mean_agg): one 256-thread block (4 waves) per row:
//   Phase 1: stage cols in LDS, dedup (back-check), compact via LDS atomic
//   Phase 2: waves split unique cols, branch-free float4 gathers, 2-deep unrolled
//   Phase 3: LDS reduction of 4 wave-partials, scale by 1/count, store

#define DFEAT  300
#define NCHUNK 75        // DFEAT / 4
#define COLS_CAP 512     // LDS staging capacity (max realistic deg ~60)
#define NWAVE  4

__global__ __launch_bounds__(256) void build_rowptr(
    const int* __restrict__ row_idx, int E, int B, int* __restrict__ row_ptr)
{
    const int e = blockIdx.x * 256 + threadIdx.x;
    if (e >= E) return;
    const int r     = row_idx[e];
    const int rprev = (e == 0) ? -1 : row_idx[e - 1];
    for (int x = rprev + 1; x <= r; ++x) row_ptr[x] = e;   // lower_bound for rows (rprev, r]
    if (e == E - 1) {
        for (int x = r + 1; x <= B; ++x) row_ptr[x] = E;   // tail + row_ptr[B]
    }
}

__global__ __launch_bounds__(256) void mean_agg_kernel(
    const int* __restrict__ row_ptr,
    const int* __restrict__ col_idx,
    const float* __restrict__ embed,
    float* __restrict__ out)
{
    const int b    = blockIdx.x;
    const int tid  = threadIdx.x;        // 0..255
    const int t    = tid & 63;           // lane
    const int wave = tid >> 6;           // 0..3

    const int start = row_ptr[b];
    const int deg   = row_ptr[b + 1] - start;

    __shared__ int   s_cols[COLS_CAP];
    __shared__ int   s_uniq[COLS_CAP];
    __shared__ int   s_cnt;
    __shared__ float s_part[NWAVE][DFEAT];

    if (tid == 0) s_cnt = 0;
    for (int k = tid; k < deg && k < COLS_CAP; k += 256) s_cols[k] = col_idx[start + k];
    __syncthreads();

    // ---- Phase 1: dedup + compact (order in s_uniq doesn't matter) ----
    for (int k = tid; k < deg; k += 256) {
        const int c = (k < COLS_CAP) ? s_cols[k] : col_idx[start + k];
        bool dup = false;
        for (int i = 0; i < k; ++i) {
            const int ci = (i < COLS_CAP) ? s_cols[i] : col_idx[start + i];
            dup |= (ci == c);
        }
        if (!dup) {
            const int p = atomicAdd(&s_cnt, 1);
            if (p < COLS_CAP) s_uniq[p] = c;
        }
    }
    __syncthreads();
    const int cnt = s_cnt;

    // ---- Phase 2: branch-free gather, waves split unique cols ----
    float4 acc0 = {0.f, 0.f, 0.f, 0.f};
    float4 acc1 = {0.f, 0.f, 0.f, 0.f};
    const bool hi_lane = (t < NCHUNK - 64);   // lanes 0..10 cover chunks 64..74

    int u = wave;
    for (; u + NWAVE < cnt; u += 2 * NWAVE) {
        const float4* __restrict__ p0 = (const float4*)(embed + (long long)s_uniq[u] * DFEAT);
        const float4* __restrict__ p1 = (const float4*)(embed + (long long)s_uniq[u + NWAVE] * DFEAT);
        const float4 x0 = p0[t];
        const float4 y0 = p1[t];
        acc0.x += x0.x; acc0.y += x0.y; acc0.z += x0.z; acc0.w += x0.w;
        acc0.x += y0.x; acc0.y += y0.y; acc0.z += y0.z; acc0.w += y0.w;
        if (hi_lane) {
            const float4 x1 = p0[t + 64];
            const float4 y1 = p1[t + 64];
            acc1.x += x1.x; acc1.y += x1.y; acc1.z += x1.z; acc1.w += x1.w;
            acc1.x += y1.x; acc1.y += y1.y; acc1.z += y1.z; acc1.w += y1.w;
        }
    }
    if (u < cnt) {
        const float4* __restrict__ p0 = (const float4*)(embed + (long long)s_uniq[u] * DFEAT);
        const float4 x0 = p0[t];
        acc0.x += x0.x; acc0.y += x0.y; acc0.z += x0.z; acc0.w += x0.w;
        if (hi_lane) {
            const float4 x1 = p0[t + 64];
            acc1.x += x1.x; acc1.y += x1.y; acc1.z += x1.z; acc1.w += x1.w;
        }
    }

    // ---- Phase 3: cross-wave reduction in LDS ----
    *(float4*)&s_part[wave][4 * t] = acc0;
    if (hi_lane) *(float4*)&s_part[wave][256 + 4 * t] = acc1;
    __syncthreads();

    if (tid < NCHUNK) {
        const float scale = (cnt > 0) ? (1.0f / (float)cnt) : 0.0f;
        const int o = 4 * tid;
        float4 r = {0.f, 0.f, 0.f, 0.f};
        #pragma unroll
        for (int w = 0; w < NWAVE; ++w) {
            const float4 p = *(const float4*)&s_part[w][o];
            r.x += p.x; r.y += p.y; r.z += p.z; r.w += p.w;
        }
        r.x *= scale; r.y *= scale; r.z *= scale; r.w *= scale;
        *(float4*)(out + (long long)b * DFEAT + o) = r;
    }
}

extern "C" void kernel_launch(void* const* d_in, const int* in_sizes, int n_in,
                              void* d_out, int out_size, void* d_ws, size_t ws_size,
                              hipStream_t stream) {
    const int*   row_idx = (const int*)  d_in[0];
    const int*   col_idx = (const int*)  d_in[1];
    const float* embed   = (const float*)d_in[2];
    float*       out     = (float*)      d_out;

    const int E = in_sizes[0];            // 131072
    const int B = out_size / DFEAT;       // 4096

    int* row_ptr = (int*)d_ws;            // (B+1) ints, rebuilt every call

    build_rowptr<<<(E + 255) / 256, 256, 0, stream>>>(row_idx, E, B, row_ptr);
    mean_agg_kernel<<<B, 256, 0, stream>>>(row_ptr, col_idx, embed, out);
}

// Round 4
// 111.456 us; speedup vs baseline: 1.1200x; 1.0070x over previous
//
#include <hip/hip_runtime.h>

// MeanAggregator: out[b,:] = mean over UNIQUE cols c in row-segment b of embed[c,:]
// row_idx sorted ascending; duplicate (row,col) pairs count once (.set semantics).
//
// B = 4096 rows, U = 50000, D = 300, E = 131072 (avg deg 32, max ~60).
//
// Kernel 1 (build_rowptr): CSR row pointers from sorted row_idx into d_ws.
// Kernel 2 (mean_agg): ONE WAVE PER ROW, no __syncthreads anywhere:
//   - dedup: __shfl intra-chunk compare + LDS-broadcast compare vs accepted
//     uniques (handles any deg in 64-chunks), ballot-rank compaction into a
//     per-wave LDS unique list
//   - gather: 4-deep unrolled float4 loads (8 loads in flight incl. hi chunks),
//     lane t covers chunk t, lanes 0..10 also chunk 64+t (75 chunks = 300 f32)
//   - direct scaled store (no cross-wave reduction, no barrier convoying)

#define DFEAT  300
#define NCHUNK 75        // DFEAT / 4
#define CAP    128       // per-wave unique-col capacity (max realistic deg ~60)
#define WPB    4         // waves per 256-thread block

__global__ __launch_bounds__(256) void build_rowptr(
    const int* __restrict__ row_idx, int E, int B, int* __restrict__ row_ptr)
{
    const int e = blockIdx.x * 256 + threadIdx.x;
    if (e >= E) return;
    const int r     = row_idx[e];
    const int rprev = (e == 0) ? -1 : row_idx[e - 1];
    for (int x = rprev + 1; x <= r; ++x) row_ptr[x] = e;   // lower_bound for rows (rprev, r]
    if (e == E - 1) {
        for (int x = r + 1; x <= B; ++x) row_ptr[x] = E;   // tail + row_ptr[B]
    }
}

__global__ __launch_bounds__(256) void mean_agg_kernel(
    const int* __restrict__ row_ptr,
    const int* __restrict__ col_idx,
    const float* __restrict__ embed,
    float* __restrict__ out,
    int B)
{
    const int lane = threadIdx.x & 63;
    const int w    = threadIdx.x >> 6;
    const int b    = blockIdx.x * WPB + w;
    if (b >= B) return;

    __shared__ int s_uniq[WPB][CAP];

    const int start = row_ptr[b];
    const int deg   = row_ptr[b + 1] - start;

    // ---- dedup + compact into s_uniq[w][0..cnt) (wave-local, no barriers) ----
    int cnt = 0;
    for (int base = 0; base < deg; base += 64) {
        const int  i     = base + lane;
        const bool valid = (i < deg);
        const int  c     = valid ? col_idx[start + i] : -1;

        bool dup = false;
        // vs uniques accepted in earlier chunks (uniform broadcast reads)
        for (int q = 0; q < cnt; ++q) dup = dup || (s_uniq[w][q] == c);
        // vs earlier lanes in this chunk
        const int jmax = (deg - base - 1 < 63) ? (deg - base - 1) : 63;
        for (int j = 0; j < jmax; ++j) {
            const int cj = __shfl(c, j);
            dup = dup || ((j < lane) && (cj == c));
        }

        const unsigned long long m = __ballot(valid && !dup);
        const int rank = __popcll(m & ((1ull << lane) - 1ull));
        if (valid && !dup) {
            const int p = cnt + rank;
            if (p < CAP) s_uniq[w][p] = c;
        }
        cnt += (int)__popcll(m);
    }
    if (cnt > CAP) cnt = CAP;   // unreachable for this dataset; safety only

    // ---- gather: 4-deep unrolled, branch-free ----
    const bool hi = (lane < NCHUNK - 64);   // lanes 0..10 cover chunks 64..74
    float4 a0 = {0.f, 0.f, 0.f, 0.f};
    float4 a1 = {0.f, 0.f, 0.f, 0.f};

    int u = 0;
    for (; u + 4 <= cnt; u += 4) {
        const float4* __restrict__ p0 = (const float4*)(embed + (size_t)s_uniq[w][u    ] * DFEAT);
        const float4* __restrict__ p1 = (const float4*)(embed + (size_t)s_uniq[w][u + 1] * DFEAT);
        const float4* __restrict__ p2 = (const float4*)(embed + (size_t)s_uniq[w][u + 2] * DFEAT);
        const float4* __restrict__ p3 = (const float4*)(embed + (size_t)s_uniq[w][u + 3] * DFEAT);
        const float4 v0 = p0[lane];
        const float4 v1 = p1[lane];
        const float4 v2 = p2[lane];
        const float4 v3 = p3[lane];
        if (hi) {
            const float4 h0 = p0[lane + 64];
            const float4 h1 = p1[lane + 64];
            const float4 h2 = p2[lane + 64];
            const float4 h3 = p3[lane + 64];
            a1.x += h0.x + h1.x + h2.x + h3.x;
            a1.y += h0.y + h1.y + h2.y + h3.y;
            a1.z += h0.z + h1.z + h2.z + h3.z;
            a1.w += h0.w + h1.w + h2.w + h3.w;
        }
        a0.x += v0.x + v1.x + v2.x + v3.x;
        a0.y += v0.y + v1.y + v2.y + v3.y;
        a0.z += v0.z + v1.z + v2.z + v3.z;
        a0.w += v0.w + v1.w + v2.w + v3.w;
    }
    for (; u < cnt; ++u) {
        const float4* __restrict__ p0 = (const float4*)(embed + (size_t)s_uniq[w][u] * DFEAT);
        const float4 v0 = p0[lane];
        a0.x += v0.x; a0.y += v0.y; a0.z += v0.z; a0.w += v0.w;
        if (hi) {
            const float4 h0 = p0[lane + 64];
            a1.x += h0.x; a1.y += h0.y; a1.z += h0.z; a1.w += h0.w;
        }
    }

    // ---- scale + store ----
    const float s = (cnt > 0) ? (1.0f / (float)cnt) : 0.0f;
    float4* __restrict__ orow = (float4*)(out + (size_t)b * DFEAT);
    float4 r0; r0.x = a0.x * s; r0.y = a0.y * s; r0.z = a0.z * s; r0.w = a0.w * s;
    orow[lane] = r0;
    if (hi) {
        float4 r1; r1.x = a1.x * s; r1.y = a1.y * s; r1.z = a1.z * s; r1.w = a1.w * s;
        orow[lane + 64] = r1;
    }
}

extern "C" void kernel_launch(void* const* d_in, const int* in_sizes, int n_in,
                              void* d_out, int out_size, void* d_ws, size_t ws_size,
                              hipStream_t stream) {
    const int*   row_idx = (const int*)  d_in[0];
    const int*   col_idx = (const int*)  d_in[1];
    const float* embed   = (const float*)d_in[2];
    float*       out     = (float*)      d_out;

    const int E = in_sizes[0];            // 131072
    const int B = out_size / DFEAT;       // 4096

    int* row_ptr = (int*)d_ws;            // (B+1) ints, rebuilt every call

    build_rowptr<<<(E + 255) / 256, 256, 0, stream>>>(row_idx, E, B, row_ptr);
    mean_agg_kernel<<<(B + WPB - 1) / WPB, 256, 0, stream>>>(row_ptr, col_idx, embed, out, B);
}